// Round 19
// baseline (1924.109 us; speedup 1.0000x reference)
//
#include <hip/hip_runtime.h>
#include <stdint.h>

#define INFV 1e9f
#define CCAP 4194304u   // compact buffer capacity (A region, 16MB / 4B)

// ---------------- ws layout (bytes) ----------------
#define SIM_OFF  0           // 1024x8192 f32 sim; DEAD after dpk -> reused as map[64][8192] u16 (1MB)
#define A_OFF    33554432    // scratch: compact keys (pre-dpk) -> A table (dpk) -> btk input
#define INVT_OFF 50331648    // 1024 f32 (dead after gemmk -> reused as carryG[7][1024] u64)
#define INVE_OFF 50335744    // 8192 f32 (dead after gemmk -> carryG tail)
#define H1_OFF   50368512    // 4096 u32
#define H2_OFF   50384896    // 4096 u32
#define H3_OFF   50401280    // 256 u32
#define SEL_OFF  50402304    // 16 u32: [0]=rank R, [1]=key prefix, [2]=dropline bits, [4]=compact count

// ---------------- norms + arange ----------------
__global__ __launch_bounds__(256) void normk(const float* __restrict__ T, const float* __restrict__ E,
                                             float* __restrict__ invt, float* __restrict__ inve,
                                             float* __restrict__ out) {
  int row = blockIdx.x;
  const float* src = (row < 1024) ? (T + (size_t)row * 1024) : (E + (size_t)(row - 1024) * 1024);
  int tid = threadIdx.x;
  float4 v = ((const float4*)src)[tid];
  float s = v.x * v.x + v.y * v.y + v.z * v.z + v.w * v.w;
  #pragma unroll
  for (int d = 1; d < 64; d <<= 1) s += __shfl_xor(s, d);
  __shared__ float wsum[4];
  if ((tid & 63) == 0) wsum[tid >> 6] = s;
  __syncthreads();
  if (tid == 0) {
    float tot = wsum[0] + wsum[1] + wsum[2] + wsum[3];
    float inv = 1.0f / fmaxf(sqrtf(tot), 1e-12f);
    if (row < 1024) invt[row] = inv; else inve[row - 1024] = inv;
  }
  if (blockIdx.x < 4) {
    int i = blockIdx.x * 256 + tid;
    out[1024 + i] = (float)i;
  }
}

__device__ inline unsigned keyOf(float f) {
  unsigned u = __float_as_uint(f);
  return (u & 0x80000000u) ? ~u : (u | 0x80000000u);
}

// ---------------- f32 GEMM: sim = (T . E^T) * invt * inve  (+ fused radix pass-0 hist) ----------------
#define AP 132
__global__ __launch_bounds__(256) void gemmk(const float* __restrict__ T, const float* __restrict__ E,
                                             const float* __restrict__ invt, const float* __restrict__ inve,
                                             float* __restrict__ sim, unsigned* __restrict__ hist) {
  __shared__ float As[16 * AP];
  __shared__ float Bs[16 * AP];
  __shared__ unsigned lh[4096];
  int tid = threadIdx.x;
  for (int b = tid; b < 4096; b += 256) lh[b] = 0;
  int i0 = blockIdx.y * 128;
  int j0 = blockIdx.x * 128;
  int tx = tid & 15, ty = tid >> 4;
  float acc[8][8];
  #pragma unroll
  for (int a = 0; a < 8; a++)
    #pragma unroll
    for (int b = 0; b < 8; b++) acc[a][b] = 0.f;

  int q = tid * 2;
  int r = q >> 2;
  int s4 = (q & 3) * 4;
  const float* Ag = T + (size_t)(i0 + r) * 1024 + s4;
  const float* Bg = E + (size_t)(j0 + r) * 1024 + s4;

  float4 a0 = *(const float4*)(Ag);
  float4 a1 = *(const float4*)(Ag + 4);
  float4 b0 = *(const float4*)(Bg);
  float4 b1 = *(const float4*)(Bg + 4);

  for (int kb = 0; kb < 64; kb++) {
    __syncthreads();
    As[(s4 + 0) * AP + r] = a0.x; As[(s4 + 1) * AP + r] = a0.y;
    As[(s4 + 2) * AP + r] = a0.z; As[(s4 + 3) * AP + r] = a0.w;
    As[(s4 + 4) * AP + r] = a1.x; As[(s4 + 5) * AP + r] = a1.y;
    As[(s4 + 6) * AP + r] = a1.z; As[(s4 + 7) * AP + r] = a1.w;
    Bs[(s4 + 0) * AP + r] = b0.x; Bs[(s4 + 1) * AP + r] = b0.y;
    Bs[(s4 + 2) * AP + r] = b0.z; Bs[(s4 + 3) * AP + r] = b0.w;
    Bs[(s4 + 4) * AP + r] = b1.x; Bs[(s4 + 5) * AP + r] = b1.y;
    Bs[(s4 + 6) * AP + r] = b1.z; Bs[(s4 + 7) * AP + r] = b1.w;
    __syncthreads();
    if (kb < 63) {
      a0 = *(const float4*)(Ag + (kb + 1) * 16);
      a1 = *(const float4*)(Ag + (kb + 1) * 16 + 4);
      b0 = *(const float4*)(Bg + (kb + 1) * 16);
      b1 = *(const float4*)(Bg + (kb + 1) * 16 + 4);
    }
    #pragma unroll
    for (int k = 0; k < 16; k++) {
      float a[8], b[8];
      *(float4*)&a[0] = *(float4*)&As[k * AP + ty * 8];
      *(float4*)&a[4] = *(float4*)&As[k * AP + ty * 8 + 4];
      *(float4*)&b[0] = *(float4*)&Bs[k * AP + tx * 8];
      *(float4*)&b[4] = *(float4*)&Bs[k * AP + tx * 8 + 4];
      #pragma unroll
      for (int ii = 0; ii < 8; ii++)
        #pragma unroll
        for (int jj = 0; jj < 8; jj++) acc[ii][jj] += a[ii] * b[jj];
    }
  }
  float ie[8];
  #pragma unroll
  for (int jj = 0; jj < 8; jj++) ie[jj] = inve[j0 + tx * 8 + jj];
  #pragma unroll
  for (int ii = 0; ii < 8; ii++) {
    float itv = invt[i0 + ty * 8 + ii];
    float o[8];
    #pragma unroll
    for (int jj = 0; jj < 8; jj++) o[jj] = acc[ii][jj] * itv * ie[jj];
    #pragma unroll
    for (int jj = 0; jj < 8; jj++) atomicAdd(&lh[keyOf(o[jj]) >> 20], 1u);
    float* dst = &sim[(size_t)(i0 + ty * 8 + ii) * 8192 + j0 + tx * 8];
    *(float4*)dst = *(float4*)&o[0];
    *(float4*)(dst + 4) = *(float4*)&o[4];
  }
  __syncthreads();
  for (int b = tid; b < 4096; b += 256) if (lh[b]) atomicAdd(&hist[b], lh[b]);
}

// ---------------- radix pass-1: hist bits 19..8 of matching keys + COMPACT matching keys ----------------
__global__ __launch_bounds__(256) void histk1(const float* __restrict__ sim, unsigned* __restrict__ hist,
                                              unsigned* __restrict__ cbuf, unsigned* __restrict__ ccnt,
                                              const unsigned* __restrict__ sel) {
  __shared__ unsigned lh[4096];
  int tid = threadIdx.x;
  int lane = tid & 63;
  for (int b = tid; b < 4096; b += 256) lh[b] = 0;
  __syncthreads();
  unsigned prefix = sel[1];
  size_t base = (size_t)blockIdx.x * 4096 + tid * 4;
  #pragma unroll
  for (int it = 0; it < 4; it++) {
    float4 f = *(const float4*)(sim + base + it * 1024);
    float vals[4] = {f.x, f.y, f.z, f.w};
    #pragma unroll
    for (int e = 0; e < 4; e++) {
      unsigned u = keyOf(vals[e]);
      bool m = ((u >> 20) == (prefix >> 20));
      if (m) atomicAdd(&lh[(u >> 8) & 0xFFFu], 1u);
      unsigned long long mask = __ballot(m);
      if (mask) {
        int cnt = __popcll(mask);
        int leader = __ffsll((long long)mask) - 1;
        unsigned bs = 0;
        if (lane == leader) bs = atomicAdd(ccnt, (unsigned)cnt);
        bs = __shfl(bs, leader);
        if (m) {
          int rank = __popcll(mask & ((1ull << lane) - 1ull));
          unsigned idx = bs + (unsigned)rank;
          if (idx < CCAP) cbuf[idx] = u;
        }
      }
    }
  }
  __syncthreads();
  for (int b = tid; b < 4096; b += 256) if (lh[b]) atomicAdd(&hist[b], lh[b]);
}

// ---------------- radix pass-2: 256-bin hist over the compact buffer ----------------
__global__ __launch_bounds__(256) void hist2k(const unsigned* __restrict__ cbuf,
                                              const unsigned* __restrict__ ccnt,
                                              unsigned* __restrict__ hist,
                                              const unsigned* __restrict__ sel) {
  __shared__ unsigned lh[256];
  int tid = threadIdx.x;
  lh[tid] = 0;
  __syncthreads();
  unsigned n = *ccnt; if (n > CCAP) n = CCAP;
  unsigned prefix = sel[1];
  for (unsigned i = blockIdx.x * 256 + tid; i < n; i += gridDim.x * 256) {
    unsigned u = cbuf[i];
    if ((u >> 8) == (prefix >> 8)) atomicAdd(&lh[u & 0xFFu], 1u);
  }
  __syncthreads();
  if (lh[tid]) atomicAdd(&hist[tid], lh[tid]);
}

__global__ __launch_bounds__(256) void scank(const unsigned* __restrict__ hist, unsigned* __restrict__ sel, int pass) {
  int tid = threadIdx.x;
  int nb = (pass == 2) ? 256 : 4096;
  int per = nb / 256;
  unsigned R = (pass == 0) ? 5872027u : sel[0];
  unsigned prefix = (pass == 0) ? 0u : sel[1];
  unsigned cnt[16];
  unsigned s = 0;
  for (int i = 0; i < per; i++) { cnt[i] = hist[tid * per + i]; s += cnt[i]; }
  unsigned incl = s;
  #pragma unroll
  for (int d = 1; d < 64; d <<= 1) { unsigned o = __shfl_up(incl, d); if ((tid & 63) >= d) incl += o; }
  __shared__ unsigned wt[4], wsc[4];
  if ((tid & 63) == 63) wt[tid >> 6] = incl;
  __syncthreads();
  if (tid < 4) {
    unsigned v = wt[tid];
    #pragma unroll
    for (int d = 1; d < 4; d <<= 1) { unsigned o = __shfl_up(v, d); if (tid >= d) v += o; }
    wsc[tid] = v;
  }
  __syncthreads();
  unsigned excl = incl - s + ((tid >> 6) ? wsc[(tid >> 6) - 1] : 0u);
  unsigned c = excl;
  for (int i = 0; i < per; i++) {
    unsigned nc = c + cnt[i];
    if (c < R && R <= nc) {
      unsigned bin = (unsigned)(tid * per + i);
      sel[0] = R - c;
      unsigned np_;
      if (pass == 0) np_ = bin << 20;
      else if (pass == 1) np_ = prefix | (bin << 8);
      else np_ = prefix | bin;
      sel[1] = np_;
      if (pass == 2) {
        unsigned key = np_;
        unsigned u = (key & 0x80000000u) ? (key ^ 0x80000000u) : ~key;
        ((float*)sel)[2] = __uint_as_float(u);
      }
    }
    c = nc;
  }
}

// ---------------- DPP helpers ----------------
template<int CTRL, int RM>
__device__ __forceinline__ float dppf(float old, float src) {
  return __int_as_float(__builtin_amdgcn_update_dpp(__float_as_int(old), __float_as_int(src), CTRL, RM, 0xf, false));
}
template<int CTRL, int RM>
__device__ __forceinline__ int dppi(int old, int src) {
  return __builtin_amdgcn_update_dpp(old, src, CTRL, RM, 0xf, false);
}

// full-wave shift-down-by-1 of x (lane l gets lane l-1's x; lane 0 gets `fill`)
__device__ __forceinline__ float wave_shr1(float x, float fill, int lane) {
  float rs  = dppf<0x111, 0xf>(INFV, x);
  float r15 = dppf<0x142, 0xa>(INFV, x);
  float r31 = dppf<0x143, 0xc>(INFV, x);
  float r = rs;
  if (lane == 16 || lane == 48) r = r15;
  if (lane == 32) r = r31;
  if (lane == 0) r = fill;
  return r;
}

// ---------------- Drop-DTW DP: 8-WG x 4-wave pipeline, fully pinned carry prefetches ----------------
// R17 structure (best known: 519us). ghop carry prefetch: asm global_load sc0 sc1, counted
// vmcnt (pinned issue + counted wait). NEW (R19): lhop LDS prefetch completion is pinned at
// END of row body via empty asm "+v"(pend) -- prevents LLVM sinking the relaxed atomic load
// to the consume point (which made every lhop row pay the LDS round trip serially). The
// load still issues early at step 2; its s_waitcnt now lands after ~300cy of row compute.
__global__ __launch_bounds__(256) void dpk(const float* __restrict__ sim,
                                           const unsigned* __restrict__ sel,
                                           unsigned long long* __restrict__ carryG,
                                           unsigned short* __restrict__ A, float* __restrict__ out) {
  int tid = threadIdx.x;
  int lane = tid & 63, w = tid >> 6;
  int wg = blockIdx.x;
  int W = wg * 4 + w;
  int col0 = wg * 1024 + tid * 4;
  float drop = ((const float*)sel)[2];
  __shared__ unsigned long long carry[3][1024];
  for (int i = tid; i < 3 * 1024; i += 256) ((unsigned long long*)carry)[i] = 0ull;
  __syncthreads();

  bool ghop = (w == 0 && wg > 0);
  bool lhop = (w > 0);

  float r[4];
  #pragma unroll
  for (int u = 0; u < 4; u++) r[u] = 0.f;
  float rlast = 0.f;
  float pbfill = 0.f;
  int jj[4];
  #pragma unroll
  for (int u = 0; u < 4; u++) jj[u] = col0 + 1 + u;

  const float* zrow = sim + col0;
  unsigned short* abase = A + (size_t)(col0 >> 7) * 2048 + (col0 & 127);

  float b0[4], b1[4], b2[4], b3[4];
  *(float4*)&b0[0] = *(const float4*)(zrow);
  *(float4*)&b1[0] = *(const float4*)(zrow + 8192);
  *(float4*)&b2[0] = *(const float4*)(zrow + 16384);
  *(float4*)&b3[0] = *(const float4*)(zrow + 24576);

  const unsigned long long* gsrc = carryG + (size_t)(wg - 1) * 1024;
  unsigned long long pend = 0ull;
  unsigned long long pq0 = 0ull, pq1 = 0ull;     // depth-2 asm-prefetched carry regs
  if (lhop) pend = __hip_atomic_load(&carry[w - 1][0], __ATOMIC_RELAXED, __HIP_MEMORY_SCOPE_WORKGROUP);
  if (ghop) {
    const unsigned long long* g0 = gsrc + 0;
    const unsigned long long* g1 = gsrc + 1;
    asm volatile("global_load_dwordx2 %0, %2, off sc0 sc1\n\t"
                 "global_load_dwordx2 %1, %3, off sc0 sc1"
                 : "+v"(pq0), "+v"(pq1) : "v"(g0), "v"(g1) : "memory");
  }

  auto body = [&](float (&dc)[4], unsigned long long& pq, int zi0) {
    unsigned want = (unsigned)(zi0 + 1) << 14;

    // 1. consume carry FIRST. ghop: counted wait for the asm prefetch; stale -> spin.
    if (ghop) {
      asm volatile("s_waitcnt vmcnt(5)" ::: "memory");
      __builtin_amdgcn_sched_barrier(0);
    }
    float cv; int ci;
    if (W > 0) {
      unsigned long long d = lhop ? pend : pq;
      if (__builtin_expect((((unsigned)d) & 0xFFFFC000u) != want, 0)) {
        int guard = 0;
        if (lhop) {
          do {
            __builtin_amdgcn_s_sleep(1);
            d = __hip_atomic_load(&carry[w - 1][zi0], __ATOMIC_RELAXED, __HIP_MEMORY_SCOPE_WORKGROUP);
          } while ((((unsigned)d) & 0xFFFFC000u) != want && ++guard < (1 << 20));
        } else {
          do {
            __builtin_amdgcn_s_sleep(1);
            d = __hip_atomic_load(gsrc + zi0, __ATOMIC_RELAXED, __HIP_MEMORY_SCOPE_AGENT);
          } while ((((unsigned)d) & 0xFFFFC000u) != want && ++guard < (1 << 20));
        }
      }
      cv = __uint_as_float((unsigned)(d >> 32));
      ci = (int)((unsigned)d & 0x3FFFu);
    } else {
      cv = INFV; ci = 0;
    }
    // 2. re-arm carry prefetch: LDS depth-1 (atomic, completion pinned at end of body),
    //    global depth-2 (asm, issue pinned)
    if (lhop && zi0 + 1 < 1024) pend = __hip_atomic_load(&carry[w - 1][zi0 + 1], __ATOMIC_RELAXED, __HIP_MEMORY_SCOPE_WORKGROUP);
    if (ghop) {
      int slot = zi0 + 2; if (slot > 1023) slot = 1023;
      const unsigned long long* gp = gsrc + slot;
      asm volatile("global_load_dwordx2 %0, %1, off sc0 sc1" : "+v"(pq) : "v"(gp) : "memory");
    }

    // 3. row compute: tv = (drop - sim) + B_prev  (identical ops/order to reference)
    float fill = (W == 0) ? ((zi0 == 0) ? 0.f : INFV) : pbfill;
    float pb0 = wave_shr1(rlast, fill, lane);
    float tv[4];
    { float zx0 = drop - dc[0]; tv[0] = zx0 + pb0; }
    #pragma unroll
    for (int u = 1; u < 4; u++) { float zxu = drop - dc[u]; tv[u] = zxu + r[u - 1]; }
    // 4. sim prefetch re-arm (unconditional, clamped row -> symmetric vmem counts)
    {
      int nr = zi0 + 4; if (nr > 1023) nr = 1023;
      *(float4*)&dc[0] = *(const float4*)(zrow + (size_t)nr * 8192);
    }
    // 5. in-thread inclusive prefix-min + latest-tie argmin
    int li[4];
    r[0] = tv[0]; li[0] = jj[0];
    #pragma unroll
    for (int u = 1; u < 4; u++) {
      bool t = (tv[u] <= r[u - 1]);
      r[u] = t ? tv[u] : r[u - 1];
      li[u] = t ? jj[u] : li[u - 1];
    }
    float v = r[3]; int ix = li[3];
    { float sv = dppf<0x111, 0xf>(INFV, v); int si = dppi<0x111, 0xf>(0, ix); if (sv < v) { v = sv; ix = si; } }
    { float sv = dppf<0x112, 0xf>(INFV, v); int si = dppi<0x112, 0xf>(0, ix); if (sv < v) { v = sv; ix = si; } }
    { float sv = dppf<0x114, 0xf>(INFV, v); int si = dppi<0x114, 0xf>(0, ix); if (sv < v) { v = sv; ix = si; } }
    { float sv = dppf<0x118, 0xf>(INFV, v); int si = dppi<0x118, 0xf>(0, ix); if (sv < v) { v = sv; ix = si; } }
    { float sv = dppf<0x142, 0xa>(INFV, v); int si = dppi<0x142, 0xa>(0, ix); if (sv < v) { v = sv; ix = si; } }
    { float sv = dppf<0x143, 0xc>(INFV, v); int si = dppi<0x143, 0xc>(0, ix); if (sv < v) { v = sv; ix = si; } }
    float exv = dppf<0x111, 0xf>(INFV, v); int exi = dppi<0x111, 0xf>(0, ix);
    float e15 = dppf<0x142, 0xa>(INFV, v); int i15 = dppi<0x142, 0xa>(0, ix);
    float e31 = dppf<0x143, 0xc>(INFV, v); int i31 = dppi<0x143, 0xc>(0, ix);
    if (lane == 16 || lane == 48) { exv = e15; exi = i15; }
    if (lane == 32) { exv = e31; exi = i31; }

    // 6. publish combined C_W(zi0) = combine(C_{W-1}, T_W); own cols later -> win ties
    if (lane == 63 && W < 31) {
      bool t = (v <= cv);
      float cov = t ? v : cv;
      int coi = t ? ix : ci;
      unsigned long long pd = ((unsigned long long)__float_as_uint(cov) << 32)
                            | (unsigned)(coi & 0x3FFF) | (unsigned long long)want;
      if (w < 3) __hip_atomic_store(&carry[w][zi0], pd, __ATOMIC_RELAXED, __HIP_MEMORY_SCOPE_WORKGROUP);
      else       __hip_atomic_store(&carryG[(size_t)wg * 1024 + zi0], pd, __ATOMIC_RELAXED, __HIP_MEMORY_SCOPE_AGENT);
    }

    // 7. init = combine(received carry, wave-exclusive); PARALLEL per-column merge; A-store
    float pv; int pi;
    { bool t = (exv <= cv); pv = t ? exv : cv; pi = t ? exi : ci; }
    #pragma unroll
    for (int u = 0; u < 4; u++) {
      bool t = (r[u] <= pv);
      r[u] = t ? r[u] : pv;
      li[u] = t ? li[u] : pi;
    }
    rlast = r[3];
    pbfill = cv;

    unsigned pk0 = (unsigned)li[0] | ((unsigned)li[1] << 16);
    unsigned pk1 = (unsigned)li[2] | ((unsigned)li[3] << 16);
    *(uint2*)(abase + (size_t)(zi0 >> 4) * (64 * 2048) + ((zi0 & 15) << 7)) = make_uint2(pk0, pk1);

    // 8. pin lhop prefetch completion HERE (end of body): the ds load issued at step 2
    //    must be materialized by this asm -> its waitcnt lands after the row compute.
    if (lhop) asm volatile("" : "+v"(pend));
  };

  for (int zz = 0; zz < 1024; zz += 4) {
    body(b0, pq0, zz);
    body(b1, pq1, zz + 1);
    body(b2, pq0, zz + 2);
    body(b3, pq1, zz + 3);
  }
  if (wg == 7 && tid == 255) out[2048] = rlast;   // min(D0f[K,N], D1f[K,N])
}

// ---------------- parallel backtrack ----------------
__global__ __launch_bounds__(256) void btk1(const unsigned short* __restrict__ A,
                                            unsigned short* __restrict__ map) {
  int g = blockIdx.x * 256 + threadIdx.x;
  int b = g >> 13;
  int j = (g & 8191) + 1;
  #pragma unroll
  for (int s = 15; s >= 0; --s) {
    int col = (j > 0) ? (j - 1) : 0;
    int p = A[(size_t)(b * 64 + (col >> 7)) * 2048 + (s << 7) + (col & 127)];
    j = p - 1;
  }
  map[g] = (unsigned short)j;
}

__global__ void btk2(const unsigned short* __restrict__ A, const unsigned short* __restrict__ map,
                     float* __restrict__ out) {
  __shared__ int entry[64];
  int t = threadIdx.x;
  if (t == 0) {
    int jb = 8192;
    for (int b = 63; b >= 0; --b) {
      entry[b] = jb;
      jb = map[b * 8192 + (jb - 1)];
    }
  }
  __syncthreads();
  if (t < 64) {
    int b = t;
    int j = entry[b];
    for (int s = 15; s >= 0; --s) {
      int col = j - 1;
      int p = A[(size_t)(b * 64 + (col >> 7)) * 2048 + (s << 7) + (col & 127)];
      out[b * 16 + s] = (float)(p - 1);
      j = p - 1;
    }
  }
}

extern "C" void kernel_launch(void* const* d_in, const int* in_sizes, int n_in,
                              void* d_out, int out_size, void* d_ws, size_t ws_size,
                              hipStream_t stream) {
  (void)in_sizes; (void)n_in; (void)out_size; (void)ws_size;
  const float* T = (const float*)d_in[0];
  const float* E = (const float*)d_in[1];
  char* ws = (char*)d_ws;
  float* sim = (float*)(ws + SIM_OFF);
  unsigned short* A = (unsigned short*)(ws + A_OFF);
  unsigned* cbuf = (unsigned*)(ws + A_OFF);          // A region is scratch pre-dpk
  float* invt = (float*)(ws + INVT_OFF);
  float* inve = (float*)(ws + INVE_OFF);
  unsigned* h1 = (unsigned*)(ws + H1_OFF);
  unsigned* h2 = (unsigned*)(ws + H2_OFF);
  unsigned* h3 = (unsigned*)(ws + H3_OFF);
  unsigned* sel = (unsigned*)(ws + SEL_OFF);
  unsigned long long* carryG = (unsigned long long*)(ws + INVT_OFF);
  unsigned short* map = (unsigned short*)(ws + SIM_OFF);
  float* out = (float*)d_out;

  hipMemsetAsync(ws + H1_OFF, 0, 16384 + 16384 + 1024 + 64, stream);
  normk<<<9216, 256, 0, stream>>>(T, E, invt, inve, out);
  gemmk<<<dim3(64, 8), 256, 0, stream>>>(T, E, invt, inve, sim, h1);     // fused pass-0 hist
  scank<<<1, 256, 0, stream>>>(h1, sel, 0);
  histk1<<<2048, 256, 0, stream>>>(sim, h2, cbuf, &sel[4], sel);         // pass-1 hist + compact
  scank<<<1, 256, 0, stream>>>(h2, sel, 1);
  hist2k<<<32, 256, 0, stream>>>(cbuf, &sel[4], h3, sel);                // pass-2 over compact buf
  scank<<<1, 256, 0, stream>>>(h3, sel, 2);
  hipMemsetAsync(ws + INVT_OFF, 0, 7 * 1024 * 8, stream);                // zero carryG
  dpk<<<8, 256, 0, stream>>>(sim, sel, carryG, A, out);
  btk1<<<2048, 256, 0, stream>>>(A, map);
  btk2<<<1, 64, 0, stream>>>(A, map, out);
}

// Round 20
// 794.592 us; speedup vs baseline: 2.4215x; 2.4215x over previous
//
#include <hip/hip_runtime.h>
#include <stdint.h>

#define INFV 1e9f

// ---------------- ws layout (bytes) ----------------
#define SIM_OFF  0           // 1024x8192 f32 sim; DEAD after dpk -> reused as map[64][8192] u16 (1MB)
#define A_OFF    33554432    // 1024x8192 u16 prefix-argmin table, tiled 16x128 (4KB tiles)
#define INVT_OFF 50331648    // 1024 f32 (dead after gemmk -> reused as carryG[7][1024] u64)
#define INVE_OFF 50335744    // 8192 f32 (dead after gemmk -> carryG tail)
#define H1_OFF   50368512    // 4096 u32
#define H2_OFF   50384896    // 4096 u32
#define H3_OFF   50401280    // 256 u32
#define SEL_OFF  50402304    // 16 u32: [0]=rank R, [1]=key prefix, [2]=dropline f32 bits

// ---------------- norms + arange ----------------
__global__ __launch_bounds__(256) void normk(const float* __restrict__ T, const float* __restrict__ E,
                                             float* __restrict__ invt, float* __restrict__ inve,
                                             float* __restrict__ out) {
  int row = blockIdx.x;
  const float* src = (row < 1024) ? (T + (size_t)row * 1024) : (E + (size_t)(row - 1024) * 1024);
  int tid = threadIdx.x;
  float4 v = ((const float4*)src)[tid];
  float s = v.x * v.x + v.y * v.y + v.z * v.z + v.w * v.w;
  #pragma unroll
  for (int d = 1; d < 64; d <<= 1) s += __shfl_xor(s, d);
  __shared__ float wsum[4];
  if ((tid & 63) == 0) wsum[tid >> 6] = s;
  __syncthreads();
  if (tid == 0) {
    float tot = wsum[0] + wsum[1] + wsum[2] + wsum[3];
    float inv = 1.0f / fmaxf(sqrtf(tot), 1e-12f);
    if (row < 1024) invt[row] = inv; else inve[row - 1024] = inv;
  }
  if (blockIdx.x < 4) {
    int i = blockIdx.x * 256 + tid;
    out[1024 + i] = (float)i;
  }
}

__device__ inline unsigned keyOf(float f) {
  unsigned u = __float_as_uint(f);
  return (u & 0x80000000u) ? ~u : (u | 0x80000000u);
}

// ---------------- f32 GEMM: sim = (T . E^T) * invt * inve  (+ fused radix pass-0 hist) ----------------
#define AP 132
__global__ __launch_bounds__(256) void gemmk(const float* __restrict__ T, const float* __restrict__ E,
                                             const float* __restrict__ invt, const float* __restrict__ inve,
                                             float* __restrict__ sim, unsigned* __restrict__ hist) {
  __shared__ float As[16 * AP];
  __shared__ float Bs[16 * AP];
  __shared__ unsigned lh[4096];
  int tid = threadIdx.x;
  for (int b = tid; b < 4096; b += 256) lh[b] = 0;
  int i0 = blockIdx.y * 128;
  int j0 = blockIdx.x * 128;
  int tx = tid & 15, ty = tid >> 4;
  float acc[8][8];
  #pragma unroll
  for (int a = 0; a < 8; a++)
    #pragma unroll
    for (int b = 0; b < 8; b++) acc[a][b] = 0.f;

  int q = tid * 2;
  int r = q >> 2;
  int s4 = (q & 3) * 4;
  const float* Ag = T + (size_t)(i0 + r) * 1024 + s4;
  const float* Bg = E + (size_t)(j0 + r) * 1024 + s4;

  float4 a0 = *(const float4*)(Ag);
  float4 a1 = *(const float4*)(Ag + 4);
  float4 b0 = *(const float4*)(Bg);
  float4 b1 = *(const float4*)(Bg + 4);

  for (int kb = 0; kb < 64; kb++) {
    __syncthreads();
    As[(s4 + 0) * AP + r] = a0.x; As[(s4 + 1) * AP + r] = a0.y;
    As[(s4 + 2) * AP + r] = a0.z; As[(s4 + 3) * AP + r] = a0.w;
    As[(s4 + 4) * AP + r] = a1.x; As[(s4 + 5) * AP + r] = a1.y;
    As[(s4 + 6) * AP + r] = a1.z; As[(s4 + 7) * AP + r] = a1.w;
    Bs[(s4 + 0) * AP + r] = b0.x; Bs[(s4 + 1) * AP + r] = b0.y;
    Bs[(s4 + 2) * AP + r] = b0.z; Bs[(s4 + 3) * AP + r] = b0.w;
    Bs[(s4 + 4) * AP + r] = b1.x; Bs[(s4 + 5) * AP + r] = b1.y;
    Bs[(s4 + 6) * AP + r] = b1.z; Bs[(s4 + 7) * AP + r] = b1.w;
    __syncthreads();
    if (kb < 63) {
      a0 = *(const float4*)(Ag + (kb + 1) * 16);
      a1 = *(const float4*)(Ag + (kb + 1) * 16 + 4);
      b0 = *(const float4*)(Bg + (kb + 1) * 16);
      b1 = *(const float4*)(Bg + (kb + 1) * 16 + 4);
    }
    #pragma unroll
    for (int k = 0; k < 16; k++) {
      float a[8], b[8];
      *(float4*)&a[0] = *(float4*)&As[k * AP + ty * 8];
      *(float4*)&a[4] = *(float4*)&As[k * AP + ty * 8 + 4];
      *(float4*)&b[0] = *(float4*)&Bs[k * AP + tx * 8];
      *(float4*)&b[4] = *(float4*)&Bs[k * AP + tx * 8 + 4];
      #pragma unroll
      for (int ii = 0; ii < 8; ii++)
        #pragma unroll
        for (int jj = 0; jj < 8; jj++) acc[ii][jj] += a[ii] * b[jj];
    }
  }
  float ie[8];
  #pragma unroll
  for (int jj = 0; jj < 8; jj++) ie[jj] = inve[j0 + tx * 8 + jj];
  #pragma unroll
  for (int ii = 0; ii < 8; ii++) {
    float itv = invt[i0 + ty * 8 + ii];
    float o[8];
    #pragma unroll
    for (int jj = 0; jj < 8; jj++) o[jj] = acc[ii][jj] * itv * ie[jj];
    #pragma unroll
    for (int jj = 0; jj < 8; jj++) atomicAdd(&lh[keyOf(o[jj]) >> 20], 1u);
    float* dst = &sim[(size_t)(i0 + ty * 8 + ii) * 8192 + j0 + tx * 8];
    *(float4*)dst = *(float4*)&o[0];
    *(float4*)(dst + 4) = *(float4*)&o[4];
  }
  __syncthreads();
  for (int b = tid; b < 4096; b += 256) if (lh[b]) atomicAdd(&hist[b], lh[b]);
}

// ---------------- exact k-th largest: radix refine passes 1,2 (full-scan, R17 scheme) ----------------
__global__ __launch_bounds__(256) void histk(const float* __restrict__ sim, unsigned* __restrict__ hist,
                                             const unsigned* __restrict__ sel, int pass) {
  __shared__ unsigned lh[4096];
  int tid = threadIdx.x;
  int nb = (pass == 2) ? 256 : 4096;
  for (int b = tid; b < nb; b += 256) lh[b] = 0;
  __syncthreads();
  unsigned prefix = sel[1];
  size_t base = (size_t)blockIdx.x * 4096 + tid * 4;
  #pragma unroll
  for (int it = 0; it < 4; it++) {
    float4 f = *(const float4*)(sim + base + it * 1024);
    float vals[4] = {f.x, f.y, f.z, f.w};
    #pragma unroll
    for (int e = 0; e < 4; e++) {
      unsigned u = keyOf(vals[e]);
      if (pass == 1) {
        if ((u >> 20) == (prefix >> 20)) atomicAdd(&lh[(u >> 8) & 0xFFFu], 1u);
      } else {
        if ((u >> 8) == (prefix >> 8)) atomicAdd(&lh[u & 0xFFu], 1u);
      }
    }
  }
  __syncthreads();
  for (int b = tid; b < nb; b += 256) if (lh[b]) atomicAdd(&hist[b], lh[b]);
}

__global__ __launch_bounds__(256) void scank(const unsigned* __restrict__ hist, unsigned* __restrict__ sel, int pass) {
  int tid = threadIdx.x;
  int nb = (pass == 2) ? 256 : 4096;
  int per = nb / 256;
  unsigned R = (pass == 0) ? 5872027u : sel[0];
  unsigned prefix = (pass == 0) ? 0u : sel[1];
  unsigned cnt[16];
  unsigned s = 0;
  for (int i = 0; i < per; i++) { cnt[i] = hist[tid * per + i]; s += cnt[i]; }
  unsigned incl = s;
  #pragma unroll
  for (int d = 1; d < 64; d <<= 1) { unsigned o = __shfl_up(incl, d); if ((tid & 63) >= d) incl += o; }
  __shared__ unsigned wt[4], wsc[4];
  if ((tid & 63) == 63) wt[tid >> 6] = incl;
  __syncthreads();
  if (tid < 4) {
    unsigned v = wt[tid];
    #pragma unroll
    for (int d = 1; d < 4; d <<= 1) { unsigned o = __shfl_up(v, d); if (tid >= d) v += o; }
    wsc[tid] = v;
  }
  __syncthreads();
  unsigned excl = incl - s + ((tid >> 6) ? wsc[(tid >> 6) - 1] : 0u);
  unsigned c = excl;
  for (int i = 0; i < per; i++) {
    unsigned nc = c + cnt[i];
    if (c < R && R <= nc) {
      unsigned bin = (unsigned)(tid * per + i);
      sel[0] = R - c;
      unsigned np_;
      if (pass == 0) np_ = bin << 20;
      else if (pass == 1) np_ = prefix | (bin << 8);
      else np_ = prefix | bin;
      sel[1] = np_;
      if (pass == 2) {
        unsigned key = np_;
        unsigned u = (key & 0x80000000u) ? (key ^ 0x80000000u) : ~key;
        ((float*)sel)[2] = __uint_as_float(u);
      }
    }
    c = nc;
  }
}

// ---------------- DPP helpers ----------------
template<int CTRL, int RM>
__device__ __forceinline__ float dppf(float old, float src) {
  return __int_as_float(__builtin_amdgcn_update_dpp(__float_as_int(old), __float_as_int(src), CTRL, RM, 0xf, false));
}
template<int CTRL, int RM>
__device__ __forceinline__ int dppi(int old, int src) {
  return __builtin_amdgcn_update_dpp(old, src, CTRL, RM, 0xf, false);
}

// full-wave shift-down-by-1 of x (lane l gets lane l-1's x; lane 0 gets `fill`)
__device__ __forceinline__ float wave_shr1(float x, float fill, int lane) {
  float rs  = dppf<0x111, 0xf>(INFV, x);
  float r15 = dppf<0x142, 0xa>(INFV, x);
  float r31 = dppf<0x143, 0xc>(INFV, x);
  float r = rs;
  if (lane == 16 || lane == 48) r = r15;
  if (lane == 32) r = r31;
  if (lane == 0) r = fill;
  return r;
}

// ---------------- Drop-DTW DP: 8-WG x 4-wave pipeline, pinned carry prefetches (R17+pin) ----------------
__global__ __launch_bounds__(256) void dpk(const float* __restrict__ sim,
                                           const unsigned* __restrict__ sel,
                                           unsigned long long* __restrict__ carryG,
                                           unsigned short* __restrict__ A, float* __restrict__ out) {
  int tid = threadIdx.x;
  int lane = tid & 63, w = tid >> 6;
  int wg = blockIdx.x;
  int W = wg * 4 + w;
  int col0 = wg * 1024 + tid * 4;
  float drop = ((const float*)sel)[2];
  __shared__ unsigned long long carry[3][1024];
  for (int i = tid; i < 3 * 1024; i += 256) ((unsigned long long*)carry)[i] = 0ull;
  __syncthreads();

  bool ghop = (w == 0 && wg > 0);
  bool lhop = (w > 0);

  float r[4];
  #pragma unroll
  for (int u = 0; u < 4; u++) r[u] = 0.f;
  float rlast = 0.f;
  float pbfill = 0.f;
  int jj[4];
  #pragma unroll
  for (int u = 0; u < 4; u++) jj[u] = col0 + 1 + u;

  const float* zrow = sim + col0;
  unsigned short* abase = A + (size_t)(col0 >> 7) * 2048 + (col0 & 127);

  float b0[4], b1[4], b2[4], b3[4];
  *(float4*)&b0[0] = *(const float4*)(zrow);
  *(float4*)&b1[0] = *(const float4*)(zrow + 8192);
  *(float4*)&b2[0] = *(const float4*)(zrow + 16384);
  *(float4*)&b3[0] = *(const float4*)(zrow + 24576);

  const unsigned long long* gsrc = carryG + (size_t)(wg - 1) * 1024;
  unsigned long long pend = 0ull;
  unsigned long long pq0 = 0ull, pq1 = 0ull;
  if (lhop) pend = __hip_atomic_load(&carry[w - 1][0], __ATOMIC_RELAXED, __HIP_MEMORY_SCOPE_WORKGROUP);
  if (ghop) {
    const unsigned long long* g0 = gsrc + 0;
    const unsigned long long* g1 = gsrc + 1;
    asm volatile("global_load_dwordx2 %0, %2, off sc0 sc1\n\t"
                 "global_load_dwordx2 %1, %3, off sc0 sc1"
                 : "+v"(pq0), "+v"(pq1) : "v"(g0), "v"(g1) : "memory");
  }

  auto body = [&](float (&dc)[4], unsigned long long& pq, int zi0) {
    unsigned want = (unsigned)(zi0 + 1) << 14;

    // 1. consume carry FIRST. ghop: counted wait for the asm prefetch; stale -> spin.
    if (ghop) {
      asm volatile("s_waitcnt vmcnt(5)" ::: "memory");
      __builtin_amdgcn_sched_barrier(0);
    }
    float cv; int ci;
    if (W > 0) {
      unsigned long long d = lhop ? pend : pq;
      if (__builtin_expect((((unsigned)d) & 0xFFFFC000u) != want, 0)) {
        int guard = 0;
        if (lhop) {
          do {
            __builtin_amdgcn_s_sleep(1);
            d = __hip_atomic_load(&carry[w - 1][zi0], __ATOMIC_RELAXED, __HIP_MEMORY_SCOPE_WORKGROUP);
          } while ((((unsigned)d) & 0xFFFFC000u) != want && ++guard < (1 << 20));
        } else {
          do {
            __builtin_amdgcn_s_sleep(1);
            d = __hip_atomic_load(gsrc + zi0, __ATOMIC_RELAXED, __HIP_MEMORY_SCOPE_AGENT);
          } while ((((unsigned)d) & 0xFFFFC000u) != want && ++guard < (1 << 20));
        }
      }
      cv = __uint_as_float((unsigned)(d >> 32));
      ci = (int)((unsigned)d & 0x3FFFu);
    } else {
      cv = INFV; ci = 0;
    }
    // 2. re-arm carry prefetch: LDS depth-1 (completion pinned at end of body),
    //    global depth-2 (asm, issue pinned)
    if (lhop && zi0 + 1 < 1024) pend = __hip_atomic_load(&carry[w - 1][zi0 + 1], __ATOMIC_RELAXED, __HIP_MEMORY_SCOPE_WORKGROUP);
    if (ghop) {
      int slot = zi0 + 2; if (slot > 1023) slot = 1023;
      const unsigned long long* gp = gsrc + slot;
      asm volatile("global_load_dwordx2 %0, %1, off sc0 sc1" : "+v"(pq) : "v"(gp) : "memory");
    }

    // 3. row compute: tv = (drop - sim) + B_prev  (identical ops/order to reference)
    float fill = (W == 0) ? ((zi0 == 0) ? 0.f : INFV) : pbfill;
    float pb0 = wave_shr1(rlast, fill, lane);
    float tv[4];
    { float zx0 = drop - dc[0]; tv[0] = zx0 + pb0; }
    #pragma unroll
    for (int u = 1; u < 4; u++) { float zxu = drop - dc[u]; tv[u] = zxu + r[u - 1]; }
    // 4. sim prefetch re-arm (unconditional, clamped row -> symmetric vmem counts)
    {
      int nr = zi0 + 4; if (nr > 1023) nr = 1023;
      *(float4*)&dc[0] = *(const float4*)(zrow + (size_t)nr * 8192);
    }
    // 5. in-thread inclusive prefix-min + latest-tie argmin
    int li[4];
    r[0] = tv[0]; li[0] = jj[0];
    #pragma unroll
    for (int u = 1; u < 4; u++) {
      bool t = (tv[u] <= r[u - 1]);
      r[u] = t ? tv[u] : r[u - 1];
      li[u] = t ? jj[u] : li[u - 1];
    }
    float v = r[3]; int ix = li[3];
    { float sv = dppf<0x111, 0xf>(INFV, v); int si = dppi<0x111, 0xf>(0, ix); if (sv < v) { v = sv; ix = si; } }
    { float sv = dppf<0x112, 0xf>(INFV, v); int si = dppi<0x112, 0xf>(0, ix); if (sv < v) { v = sv; ix = si; } }
    { float sv = dppf<0x114, 0xf>(INFV, v); int si = dppi<0x114, 0xf>(0, ix); if (sv < v) { v = sv; ix = si; } }
    { float sv = dppf<0x118, 0xf>(INFV, v); int si = dppi<0x118, 0xf>(0, ix); if (sv < v) { v = sv; ix = si; } }
    { float sv = dppf<0x142, 0xa>(INFV, v); int si = dppi<0x142, 0xa>(0, ix); if (sv < v) { v = sv; ix = si; } }
    { float sv = dppf<0x143, 0xc>(INFV, v); int si = dppi<0x143, 0xc>(0, ix); if (sv < v) { v = sv; ix = si; } }
    float exv = dppf<0x111, 0xf>(INFV, v); int exi = dppi<0x111, 0xf>(0, ix);
    float e15 = dppf<0x142, 0xa>(INFV, v); int i15 = dppi<0x142, 0xa>(0, ix);
    float e31 = dppf<0x143, 0xc>(INFV, v); int i31 = dppi<0x143, 0xc>(0, ix);
    if (lane == 16 || lane == 48) { exv = e15; exi = i15; }
    if (lane == 32) { exv = e31; exi = i31; }

    // 6. publish combined C_W(zi0) = combine(C_{W-1}, T_W); own cols later -> win ties
    if (lane == 63 && W < 31) {
      bool t = (v <= cv);
      float cov = t ? v : cv;
      int coi = t ? ix : ci;
      unsigned long long pd = ((unsigned long long)__float_as_uint(cov) << 32)
                            | (unsigned)(coi & 0x3FFF) | (unsigned long long)want;
      if (w < 3) __hip_atomic_store(&carry[w][zi0], pd, __ATOMIC_RELAXED, __HIP_MEMORY_SCOPE_WORKGROUP);
      else       __hip_atomic_store(&carryG[(size_t)wg * 1024 + zi0], pd, __ATOMIC_RELAXED, __HIP_MEMORY_SCOPE_AGENT);
    }

    // 7. init = combine(received carry, wave-exclusive); PARALLEL per-column merge; A-store
    float pv; int pi;
    { bool t = (exv <= cv); pv = t ? exv : cv; pi = t ? exi : ci; }
    #pragma unroll
    for (int u = 0; u < 4; u++) {
      bool t = (r[u] <= pv);
      r[u] = t ? r[u] : pv;
      li[u] = t ? li[u] : pi;
    }
    rlast = r[3];
    pbfill = cv;

    unsigned pk0 = (unsigned)li[0] | ((unsigned)li[1] << 16);
    unsigned pk1 = (unsigned)li[2] | ((unsigned)li[3] << 16);
    *(uint2*)(abase + (size_t)(zi0 >> 4) * (64 * 2048) + ((zi0 & 15) << 7)) = make_uint2(pk0, pk1);

    // 8. pin lhop prefetch completion at end of body (load issued at step 2 -> its
    //    waitcnt lands here, after the row compute, not at next row's consume)
    if (lhop) asm volatile("" : "+v"(pend));
  };

  for (int zz = 0; zz < 1024; zz += 4) {
    body(b0, pq0, zz);
    body(b1, pq1, zz + 1);
    body(b2, pq0, zz + 2);
    body(b3, pq1, zz + 3);
  }
  if (wg == 7 && tid == 255) out[2048] = rlast;   // min(D0f[K,N], D1f[K,N])
}

// ---------------- parallel backtrack ----------------
__global__ __launch_bounds__(256) void btk1(const unsigned short* __restrict__ A,
                                            unsigned short* __restrict__ map) {
  int g = blockIdx.x * 256 + threadIdx.x;
  int b = g >> 13;
  int j = (g & 8191) + 1;
  #pragma unroll
  for (int s = 15; s >= 0; --s) {
    int col = (j > 0) ? (j - 1) : 0;
    int p = A[(size_t)(b * 64 + (col >> 7)) * 2048 + (s << 7) + (col & 127)];
    j = p - 1;
  }
  map[g] = (unsigned short)j;
}

__global__ void btk2(const unsigned short* __restrict__ A, const unsigned short* __restrict__ map,
                     float* __restrict__ out) {
  __shared__ int entry[64];
  int t = threadIdx.x;
  if (t == 0) {
    int jb = 8192;
    for (int b = 63; b >= 0; --b) {
      entry[b] = jb;
      jb = map[b * 8192 + (jb - 1)];
    }
  }
  __syncthreads();
  if (t < 64) {
    int b = t;
    int j = entry[b];
    for (int s = 15; s >= 0; --s) {
      int col = j - 1;
      int p = A[(size_t)(b * 64 + (col >> 7)) * 2048 + (s << 7) + (col & 127)];
      out[b * 16 + s] = (float)(p - 1);
      j = p - 1;
    }
  }
}

extern "C" void kernel_launch(void* const* d_in, const int* in_sizes, int n_in,
                              void* d_out, int out_size, void* d_ws, size_t ws_size,
                              hipStream_t stream) {
  (void)in_sizes; (void)n_in; (void)out_size; (void)ws_size;
  const float* T = (const float*)d_in[0];
  const float* E = (const float*)d_in[1];
  char* ws = (char*)d_ws;
  float* sim = (float*)(ws + SIM_OFF);
  unsigned short* A = (unsigned short*)(ws + A_OFF);
  float* invt = (float*)(ws + INVT_OFF);
  float* inve = (float*)(ws + INVE_OFF);
  unsigned* h1 = (unsigned*)(ws + H1_OFF);
  unsigned* h2 = (unsigned*)(ws + H2_OFF);
  unsigned* h3 = (unsigned*)(ws + H3_OFF);
  unsigned* sel = (unsigned*)(ws + SEL_OFF);
  unsigned long long* carryG = (unsigned long long*)(ws + INVT_OFF);
  unsigned short* map = (unsigned short*)(ws + SIM_OFF);
  float* out = (float*)d_out;

  hipMemsetAsync(ws + H1_OFF, 0, 16384 + 16384 + 1024 + 64, stream);
  normk<<<9216, 256, 0, stream>>>(T, E, invt, inve, out);
  gemmk<<<dim3(64, 8), 256, 0, stream>>>(T, E, invt, inve, sim, h1);   // fused pass-0 hist
  scank<<<1, 256, 0, stream>>>(h1, sel, 0);
  histk<<<2048, 256, 0, stream>>>(sim, h2, sel, 1);
  scank<<<1, 256, 0, stream>>>(h2, sel, 1);
  histk<<<2048, 256, 0, stream>>>(sim, h3, sel, 2);
  scank<<<1, 256, 0, stream>>>(h3, sel, 2);
  hipMemsetAsync(ws + INVT_OFF, 0, 7 * 1024 * 8, stream);   // zero carryG
  dpk<<<8, 256, 0, stream>>>(sim, sel, carryG, A, out);
  btk1<<<2048, 256, 0, stream>>>(A, map);
  btk2<<<1, 64, 0, stream>>>(A, map, out);
}

// Round 21
// 793.965 us; speedup vs baseline: 2.4234x; 1.0008x over previous
//
#include <hip/hip_runtime.h>
#include <stdint.h>

#define INFV 1e9f

// ---------------- ws layout (bytes) ----------------
#define SIM_OFF  0           // 1024x8192 f32 sim; DEAD after dpk -> reused as map[64][8192] u16 (1MB)
#define A_OFF    33554432    // 1024x8192 u16 prefix-argmin table, tiled 16x128 (4KB tiles)
#define INVT_OFF 50331648    // 1024 f32 (dead after gemmk -> reused as carryG[7][1024] u64)
#define INVE_OFF 50335744    // 8192 f32 (dead after gemmk -> carryG tail)
#define H1_OFF   50368512    // 4096 u32
#define H2_OFF   50384896    // 4096 u32
#define H3_OFF   50401280    // 256 u32
#define SEL_OFF  50402304    // 16 u32: [0]=rank R, [1]=key prefix, [2]=dropline f32 bits

// ---------------- norms + arange ----------------
__global__ __launch_bounds__(256) void normk(const float* __restrict__ T, const float* __restrict__ E,
                                             float* __restrict__ invt, float* __restrict__ inve,
                                             float* __restrict__ out) {
  int row = blockIdx.x;
  const float* src = (row < 1024) ? (T + (size_t)row * 1024) : (E + (size_t)(row - 1024) * 1024);
  int tid = threadIdx.x;
  float4 v = ((const float4*)src)[tid];
  float s = v.x * v.x + v.y * v.y + v.z * v.z + v.w * v.w;
  #pragma unroll
  for (int d = 1; d < 64; d <<= 1) s += __shfl_xor(s, d);
  __shared__ float wsum[4];
  if ((tid & 63) == 0) wsum[tid >> 6] = s;
  __syncthreads();
  if (tid == 0) {
    float tot = wsum[0] + wsum[1] + wsum[2] + wsum[3];
    float inv = 1.0f / fmaxf(sqrtf(tot), 1e-12f);
    if (row < 1024) invt[row] = inv; else inve[row - 1024] = inv;
  }
  if (blockIdx.x < 4) {
    int i = blockIdx.x * 256 + tid;
    out[1024 + i] = (float)i;
  }
}

__device__ inline unsigned keyOf(float f) {
  unsigned u = __float_as_uint(f);
  return (u & 0x80000000u) ? ~u : (u | 0x80000000u);
}

// ---------------- f32 GEMM: sim = (T . E^T) * invt * inve  (+ fused radix pass-0 hist) ----------------
#define AP 132
__global__ __launch_bounds__(256) void gemmk(const float* __restrict__ T, const float* __restrict__ E,
                                             const float* __restrict__ invt, const float* __restrict__ inve,
                                             float* __restrict__ sim, unsigned* __restrict__ hist) {
  __shared__ float As[16 * AP];
  __shared__ float Bs[16 * AP];
  __shared__ unsigned lh[4096];
  int tid = threadIdx.x;
  for (int b = tid; b < 4096; b += 256) lh[b] = 0;
  int i0 = blockIdx.y * 128;
  int j0 = blockIdx.x * 128;
  int tx = tid & 15, ty = tid >> 4;
  float acc[8][8];
  #pragma unroll
  for (int a = 0; a < 8; a++)
    #pragma unroll
    for (int b = 0; b < 8; b++) acc[a][b] = 0.f;

  int q = tid * 2;
  int r = q >> 2;
  int s4 = (q & 3) * 4;
  const float* Ag = T + (size_t)(i0 + r) * 1024 + s4;
  const float* Bg = E + (size_t)(j0 + r) * 1024 + s4;

  float4 a0 = *(const float4*)(Ag);
  float4 a1 = *(const float4*)(Ag + 4);
  float4 b0 = *(const float4*)(Bg);
  float4 b1 = *(const float4*)(Bg + 4);

  for (int kb = 0; kb < 64; kb++) {
    __syncthreads();
    As[(s4 + 0) * AP + r] = a0.x; As[(s4 + 1) * AP + r] = a0.y;
    As[(s4 + 2) * AP + r] = a0.z; As[(s4 + 3) * AP + r] = a0.w;
    As[(s4 + 4) * AP + r] = a1.x; As[(s4 + 5) * AP + r] = a1.y;
    As[(s4 + 6) * AP + r] = a1.z; As[(s4 + 7) * AP + r] = a1.w;
    Bs[(s4 + 0) * AP + r] = b0.x; Bs[(s4 + 1) * AP + r] = b0.y;
    Bs[(s4 + 2) * AP + r] = b0.z; Bs[(s4 + 3) * AP + r] = b0.w;
    Bs[(s4 + 4) * AP + r] = b1.x; Bs[(s4 + 5) * AP + r] = b1.y;
    Bs[(s4 + 6) * AP + r] = b1.z; Bs[(s4 + 7) * AP + r] = b1.w;
    __syncthreads();
    if (kb < 63) {
      a0 = *(const float4*)(Ag + (kb + 1) * 16);
      a1 = *(const float4*)(Ag + (kb + 1) * 16 + 4);
      b0 = *(const float4*)(Bg + (kb + 1) * 16);
      b1 = *(const float4*)(Bg + (kb + 1) * 16 + 4);
    }
    #pragma unroll
    for (int k = 0; k < 16; k++) {
      float a[8], b[8];
      *(float4*)&a[0] = *(float4*)&As[k * AP + ty * 8];
      *(float4*)&a[4] = *(float4*)&As[k * AP + ty * 8 + 4];
      *(float4*)&b[0] = *(float4*)&Bs[k * AP + tx * 8];
      *(float4*)&b[4] = *(float4*)&Bs[k * AP + tx * 8 + 4];
      #pragma unroll
      for (int ii = 0; ii < 8; ii++)
        #pragma unroll
        for (int jj = 0; jj < 8; jj++) acc[ii][jj] += a[ii] * b[jj];
    }
  }
  float ie[8];
  #pragma unroll
  for (int jj = 0; jj < 8; jj++) ie[jj] = inve[j0 + tx * 8 + jj];
  #pragma unroll
  for (int ii = 0; ii < 8; ii++) {
    float itv = invt[i0 + ty * 8 + ii];
    float o[8];
    #pragma unroll
    for (int jj = 0; jj < 8; jj++) o[jj] = acc[ii][jj] * itv * ie[jj];
    #pragma unroll
    for (int jj = 0; jj < 8; jj++) atomicAdd(&lh[keyOf(o[jj]) >> 20], 1u);
    float* dst = &sim[(size_t)(i0 + ty * 8 + ii) * 8192 + j0 + tx * 8];
    *(float4*)dst = *(float4*)&o[0];
    *(float4*)(dst + 4) = *(float4*)&o[4];
  }
  __syncthreads();
  for (int b = tid; b < 4096; b += 256) if (lh[b]) atomicAdd(&hist[b], lh[b]);
}

// ---------------- exact k-th largest: radix refine passes 1,2 (full-scan) ----------------
__global__ __launch_bounds__(256) void histk(const float* __restrict__ sim, unsigned* __restrict__ hist,
                                             const unsigned* __restrict__ sel, int pass) {
  __shared__ unsigned lh[4096];
  int tid = threadIdx.x;
  int nb = (pass == 2) ? 256 : 4096;
  for (int b = tid; b < nb; b += 256) lh[b] = 0;
  __syncthreads();
  unsigned prefix = sel[1];
  size_t base = (size_t)blockIdx.x * 4096 + tid * 4;
  #pragma unroll
  for (int it = 0; it < 4; it++) {
    float4 f = *(const float4*)(sim + base + it * 1024);
    float vals[4] = {f.x, f.y, f.z, f.w};
    #pragma unroll
    for (int e = 0; e < 4; e++) {
      unsigned u = keyOf(vals[e]);
      if (pass == 1) {
        if ((u >> 20) == (prefix >> 20)) atomicAdd(&lh[(u >> 8) & 0xFFFu], 1u);
      } else {
        if ((u >> 8) == (prefix >> 8)) atomicAdd(&lh[u & 0xFFu], 1u);
      }
    }
  }
  __syncthreads();
  for (int b = tid; b < nb; b += 256) if (lh[b]) atomicAdd(&hist[b], lh[b]);
}

__global__ __launch_bounds__(256) void scank(const unsigned* __restrict__ hist, unsigned* __restrict__ sel, int pass) {
  int tid = threadIdx.x;
  int nb = (pass == 2) ? 256 : 4096;
  int per = nb / 256;
  unsigned R = (pass == 0) ? 5872027u : sel[0];
  unsigned prefix = (pass == 0) ? 0u : sel[1];
  unsigned cnt[16];
  unsigned s = 0;
  for (int i = 0; i < per; i++) { cnt[i] = hist[tid * per + i]; s += cnt[i]; }
  unsigned incl = s;
  #pragma unroll
  for (int d = 1; d < 64; d <<= 1) { unsigned o = __shfl_up(incl, d); if ((tid & 63) >= d) incl += o; }
  __shared__ unsigned wt[4], wsc[4];
  if ((tid & 63) == 63) wt[tid >> 6] = incl;
  __syncthreads();
  if (tid < 4) {
    unsigned v = wt[tid];
    #pragma unroll
    for (int d = 1; d < 4; d <<= 1) { unsigned o = __shfl_up(v, d); if (tid >= d) v += o; }
    wsc[tid] = v;
  }
  __syncthreads();
  unsigned excl = incl - s + ((tid >> 6) ? wsc[(tid >> 6) - 1] : 0u);
  unsigned c = excl;
  for (int i = 0; i < per; i++) {
    unsigned nc = c + cnt[i];
    if (c < R && R <= nc) {
      unsigned bin = (unsigned)(tid * per + i);
      sel[0] = R - c;
      unsigned np_;
      if (pass == 0) np_ = bin << 20;
      else if (pass == 1) np_ = prefix | (bin << 8);
      else np_ = prefix | bin;
      sel[1] = np_;
      if (pass == 2) {
        unsigned key = np_;
        unsigned u = (key & 0x80000000u) ? (key ^ 0x80000000u) : ~key;
        ((float*)sel)[2] = __uint_as_float(u);
      }
    }
    c = nc;
  }
}

// ---------------- DPP helpers ----------------
template<int CTRL, int RM>
__device__ __forceinline__ float dppf(float old, float src) {
  return __int_as_float(__builtin_amdgcn_update_dpp(__float_as_int(old), __float_as_int(src), CTRL, RM, 0xf, false));
}
template<int CTRL, int RM>
__device__ __forceinline__ int dppi(int old, int src) {
  return __builtin_amdgcn_update_dpp(old, src, CTRL, RM, 0xf, false);
}

// full-wave shift-down-by-1 of x (lane l gets lane l-1's x; lane 0 gets `fill`)
__device__ __forceinline__ float wave_shr1(float x, float fill, int lane) {
  float rs  = dppf<0x111, 0xf>(INFV, x);
  float r15 = dppf<0x142, 0xa>(INFV, x);
  float r31 = dppf<0x143, 0xc>(INFV, x);
  float r = rs;
  if (lane == 16 || lane == 48) r = r15;
  if (lane == 32) r = r31;
  if (lane == 0) r = fill;
  return r;
}

// ---------------- Drop-DTW DP: 8-WG x 4-wave pipeline, pinned prefetch + startup stagger ----------------
// R20 structure (best known: dpk 509us) + ONE-TIME STARTUP STAGGER: wave W sleeps
// (W + 3*wg) row-periods before starting (1 row per lhop link, 4 per ghop link).
// Mechanism: spin-release rate-matches consumers at lag ~T(900cy) < 2P, so the pinned
// depth-2 prefetch ALWAYS sampled pre-publish -> stale -> serialized spin load each row
// (the residual 700cy/row stall). Reactive mid-run lag restores (R14/R18) oscillate
// through the 31-link chain; a one-time startup skew establishes lag >= 4 rows on ghop
// links without oscillation (equal link periods preserve it; spin fallback still
// catches any collapse -> bit-exact, worst case = R20 + ~11us skew).
__global__ __launch_bounds__(256) void dpk(const float* __restrict__ sim,
                                           const unsigned* __restrict__ sel,
                                           unsigned long long* __restrict__ carryG,
                                           unsigned short* __restrict__ A, float* __restrict__ out) {
  int tid = threadIdx.x;
  int lane = tid & 63, w = tid >> 6;
  int wg = blockIdx.x;
  int W = wg * 4 + w;
  int col0 = wg * 1024 + tid * 4;
  float drop = ((const float*)sel)[2];
  __shared__ unsigned long long carry[3][1024];
  for (int i = tid; i < 3 * 1024; i += 256) ((unsigned long long*)carry)[i] = 0ull;
  __syncthreads();

  // startup stagger: ~512cy per unit; delay_rows = W + 3*wg (4 rows/ghop, 1 row/lhop)
  {
    int delayR = W + 3 * wg;
    for (int i = 0; i < delayR; ++i) __builtin_amdgcn_s_sleep(8);
  }

  bool ghop = (w == 0 && wg > 0);
  bool lhop = (w > 0);

  float r[4];
  #pragma unroll
  for (int u = 0; u < 4; u++) r[u] = 0.f;
  float rlast = 0.f;
  float pbfill = 0.f;
  int jj[4];
  #pragma unroll
  for (int u = 0; u < 4; u++) jj[u] = col0 + 1 + u;

  const float* zrow = sim + col0;
  unsigned short* abase = A + (size_t)(col0 >> 7) * 2048 + (col0 & 127);

  float b0[4], b1[4], b2[4], b3[4];
  *(float4*)&b0[0] = *(const float4*)(zrow);
  *(float4*)&b1[0] = *(const float4*)(zrow + 8192);
  *(float4*)&b2[0] = *(const float4*)(zrow + 16384);
  *(float4*)&b3[0] = *(const float4*)(zrow + 24576);

  const unsigned long long* gsrc = carryG + (size_t)(wg - 1) * 1024;
  unsigned long long pend = 0ull;
  unsigned long long pq0 = 0ull, pq1 = 0ull;
  if (lhop) pend = __hip_atomic_load(&carry[w - 1][0], __ATOMIC_RELAXED, __HIP_MEMORY_SCOPE_WORKGROUP);
  if (ghop) {
    const unsigned long long* g0 = gsrc + 0;
    const unsigned long long* g1 = gsrc + 1;
    asm volatile("global_load_dwordx2 %0, %2, off sc0 sc1\n\t"
                 "global_load_dwordx2 %1, %3, off sc0 sc1"
                 : "+v"(pq0), "+v"(pq1) : "v"(g0), "v"(g1) : "memory");
  }

  auto body = [&](float (&dc)[4], unsigned long long& pq, int zi0) {
    unsigned want = (unsigned)(zi0 + 1) << 14;

    // 1. consume carry FIRST. ghop: counted wait for the asm prefetch; stale -> spin.
    if (ghop) {
      asm volatile("s_waitcnt vmcnt(5)" ::: "memory");
      __builtin_amdgcn_sched_barrier(0);
    }
    float cv; int ci;
    if (W > 0) {
      unsigned long long d = lhop ? pend : pq;
      if (__builtin_expect((((unsigned)d) & 0xFFFFC000u) != want, 0)) {
        int guard = 0;
        if (lhop) {
          do {
            __builtin_amdgcn_s_sleep(1);
            d = __hip_atomic_load(&carry[w - 1][zi0], __ATOMIC_RELAXED, __HIP_MEMORY_SCOPE_WORKGROUP);
          } while ((((unsigned)d) & 0xFFFFC000u) != want && ++guard < (1 << 20));
        } else {
          do {
            __builtin_amdgcn_s_sleep(1);
            d = __hip_atomic_load(gsrc + zi0, __ATOMIC_RELAXED, __HIP_MEMORY_SCOPE_AGENT);
          } while ((((unsigned)d) & 0xFFFFC000u) != want && ++guard < (1 << 20));
        }
      }
      cv = __uint_as_float((unsigned)(d >> 32));
      ci = (int)((unsigned)d & 0x3FFFu);
    } else {
      cv = INFV; ci = 0;
    }
    // 2. re-arm carry prefetch: LDS depth-1 (completion pinned at end of body),
    //    global depth-2 (asm, issue pinned)
    if (lhop && zi0 + 1 < 1024) pend = __hip_atomic_load(&carry[w - 1][zi0 + 1], __ATOMIC_RELAXED, __HIP_MEMORY_SCOPE_WORKGROUP);
    if (ghop) {
      int slot = zi0 + 2; if (slot > 1023) slot = 1023;
      const unsigned long long* gp = gsrc + slot;
      asm volatile("global_load_dwordx2 %0, %1, off sc0 sc1" : "+v"(pq) : "v"(gp) : "memory");
    }

    // 3. row compute: tv = (drop - sim) + B_prev  (identical ops/order to reference)
    float fill = (W == 0) ? ((zi0 == 0) ? 0.f : INFV) : pbfill;
    float pb0 = wave_shr1(rlast, fill, lane);
    float tv[4];
    { float zx0 = drop - dc[0]; tv[0] = zx0 + pb0; }
    #pragma unroll
    for (int u = 1; u < 4; u++) { float zxu = drop - dc[u]; tv[u] = zxu + r[u - 1]; }
    // 4. sim prefetch re-arm (unconditional, clamped row -> symmetric vmem counts)
    {
      int nr = zi0 + 4; if (nr > 1023) nr = 1023;
      *(float4*)&dc[0] = *(const float4*)(zrow + (size_t)nr * 8192);
    }
    // 5. in-thread inclusive prefix-min + latest-tie argmin
    int li[4];
    r[0] = tv[0]; li[0] = jj[0];
    #pragma unroll
    for (int u = 1; u < 4; u++) {
      bool t = (tv[u] <= r[u - 1]);
      r[u] = t ? tv[u] : r[u - 1];
      li[u] = t ? jj[u] : li[u - 1];
    }
    float v = r[3]; int ix = li[3];
    { float sv = dppf<0x111, 0xf>(INFV, v); int si = dppi<0x111, 0xf>(0, ix); if (sv < v) { v = sv; ix = si; } }
    { float sv = dppf<0x112, 0xf>(INFV, v); int si = dppi<0x112, 0xf>(0, ix); if (sv < v) { v = sv; ix = si; } }
    { float sv = dppf<0x114, 0xf>(INFV, v); int si = dppi<0x114, 0xf>(0, ix); if (sv < v) { v = sv; ix = si; } }
    { float sv = dppf<0x118, 0xf>(INFV, v); int si = dppi<0x118, 0xf>(0, ix); if (sv < v) { v = sv; ix = si; } }
    { float sv = dppf<0x142, 0xa>(INFV, v); int si = dppi<0x142, 0xa>(0, ix); if (sv < v) { v = sv; ix = si; } }
    { float sv = dppf<0x143, 0xc>(INFV, v); int si = dppi<0x143, 0xc>(0, ix); if (sv < v) { v = sv; ix = si; } }
    float exv = dppf<0x111, 0xf>(INFV, v); int exi = dppi<0x111, 0xf>(0, ix);
    float e15 = dppf<0x142, 0xa>(INFV, v); int i15 = dppi<0x142, 0xa>(0, ix);
    float e31 = dppf<0x143, 0xc>(INFV, v); int i31 = dppi<0x143, 0xc>(0, ix);
    if (lane == 16 || lane == 48) { exv = e15; exi = i15; }
    if (lane == 32) { exv = e31; exi = i31; }

    // 6. publish combined C_W(zi0) = combine(C_{W-1}, T_W); own cols later -> win ties
    if (lane == 63 && W < 31) {
      bool t = (v <= cv);
      float cov = t ? v : cv;
      int coi = t ? ix : ci;
      unsigned long long pd = ((unsigned long long)__float_as_uint(cov) << 32)
                            | (unsigned)(coi & 0x3FFF) | (unsigned long long)want;
      if (w < 3) __hip_atomic_store(&carry[w][zi0], pd, __ATOMIC_RELAXED, __HIP_MEMORY_SCOPE_WORKGROUP);
      else       __hip_atomic_store(&carryG[(size_t)wg * 1024 + zi0], pd, __ATOMIC_RELAXED, __HIP_MEMORY_SCOPE_AGENT);
    }

    // 7. init = combine(received carry, wave-exclusive); PARALLEL per-column merge; A-store
    float pv; int pi;
    { bool t = (exv <= cv); pv = t ? exv : cv; pi = t ? exi : ci; }
    #pragma unroll
    for (int u = 0; u < 4; u++) {
      bool t = (r[u] <= pv);
      r[u] = t ? r[u] : pv;
      li[u] = t ? li[u] : pi;
    }
    rlast = r[3];
    pbfill = cv;

    unsigned pk0 = (unsigned)li[0] | ((unsigned)li[1] << 16);
    unsigned pk1 = (unsigned)li[2] | ((unsigned)li[3] << 16);
    *(uint2*)(abase + (size_t)(zi0 >> 4) * (64 * 2048) + ((zi0 & 15) << 7)) = make_uint2(pk0, pk1);

    // 8. pin lhop prefetch completion at end of body
    if (lhop) asm volatile("" : "+v"(pend));
  };

  for (int zz = 0; zz < 1024; zz += 4) {
    body(b0, pq0, zz);
    body(b1, pq1, zz + 1);
    body(b2, pq0, zz + 2);
    body(b3, pq1, zz + 3);
  }
  if (wg == 7 && tid == 255) out[2048] = rlast;   // min(D0f[K,N], D1f[K,N])
}

// ---------------- parallel backtrack ----------------
__global__ __launch_bounds__(256) void btk1(const unsigned short* __restrict__ A,
                                            unsigned short* __restrict__ map) {
  int g = blockIdx.x * 256 + threadIdx.x;
  int b = g >> 13;
  int j = (g & 8191) + 1;
  #pragma unroll
  for (int s = 15; s >= 0; --s) {
    int col = (j > 0) ? (j - 1) : 0;
    int p = A[(size_t)(b * 64 + (col >> 7)) * 2048 + (s << 7) + (col & 127)];
    j = p - 1;
  }
  map[g] = (unsigned short)j;
}

__global__ void btk2(const unsigned short* __restrict__ A, const unsigned short* __restrict__ map,
                     float* __restrict__ out) {
  __shared__ int entry[64];
  int t = threadIdx.x;
  if (t == 0) {
    int jb = 8192;
    for (int b = 63; b >= 0; --b) {
      entry[b] = jb;
      jb = map[b * 8192 + (jb - 1)];
    }
  }
  __syncthreads();
  if (t < 64) {
    int b = t;
    int j = entry[b];
    for (int s = 15; s >= 0; --s) {
      int col = j - 1;
      int p = A[(size_t)(b * 64 + (col >> 7)) * 2048 + (s << 7) + (col & 127)];
      out[b * 16 + s] = (float)(p - 1);
      j = p - 1;
    }
  }
}

extern "C" void kernel_launch(void* const* d_in, const int* in_sizes, int n_in,
                              void* d_out, int out_size, void* d_ws, size_t ws_size,
                              hipStream_t stream) {
  (void)in_sizes; (void)n_in; (void)out_size; (void)ws_size;
  const float* T = (const float*)d_in[0];
  const float* E = (const float*)d_in[1];
  char* ws = (char*)d_ws;
  float* sim = (float*)(ws + SIM_OFF);
  unsigned short* A = (unsigned short*)(ws + A_OFF);
  float* invt = (float*)(ws + INVT_OFF);
  float* inve = (float*)(ws + INVE_OFF);
  unsigned* h1 = (unsigned*)(ws + H1_OFF);
  unsigned* h2 = (unsigned*)(ws + H2_OFF);
  unsigned* h3 = (unsigned*)(ws + H3_OFF);
  unsigned* sel = (unsigned*)(ws + SEL_OFF);
  unsigned long long* carryG = (unsigned long long*)(ws + INVT_OFF);
  unsigned short* map = (unsigned short*)(ws + SIM_OFF);
  float* out = (float*)d_out;

  hipMemsetAsync(ws + H1_OFF, 0, 16384 + 16384 + 1024 + 64, stream);
  normk<<<9216, 256, 0, stream>>>(T, E, invt, inve, out);
  gemmk<<<dim3(64, 8), 256, 0, stream>>>(T, E, invt, inve, sim, h1);   // fused pass-0 hist
  scank<<<1, 256, 0, stream>>>(h1, sel, 0);
  histk<<<2048, 256, 0, stream>>>(sim, h2, sel, 1);
  scank<<<1, 256, 0, stream>>>(h2, sel, 1);
  histk<<<2048, 256, 0, stream>>>(sim, h3, sel, 2);
  scank<<<1, 256, 0, stream>>>(h3, sel, 2);
  hipMemsetAsync(ws + INVT_OFF, 0, 7 * 1024 * 8, stream);   // zero carryG
  dpk<<<8, 256, 0, stream>>>(sim, sel, carryG, A, out);
  btk1<<<2048, 256, 0, stream>>>(A, map);
  btk2<<<1, 64, 0, stream>>>(A, map, out);
}

// Round 22
// 789.442 us; speedup vs baseline: 2.4373x; 1.0057x over previous
//
#include <hip/hip_runtime.h>
#include <stdint.h>

#define INFV 1e9f

// ---------------- ws layout (bytes) ----------------
#define SIM_OFF  0           // 1024x8192 f32 sim; DEAD after dpk -> reused as map[64][8192] u16 (1MB)
#define A_OFF    33554432    // 1024x8192 u16 prefix-argmin table, tiled 16x128 (4KB tiles)
#define INVT_OFF 50331648    // 1024 f32 (dead after gemmk -> reused as carryG[7][1024] u64)
#define INVE_OFF 50335744    // 8192 f32 (dead after gemmk -> carryG tail)
#define H1_OFF   50368512    // 4096 u32
#define H2_OFF   50384896    // 4096 u32
#define H3_OFF   50401280    // 256 u32
#define SEL_OFF  50402304    // 16 u32: [0]=rank R, [1]=key prefix, [2]=dropline f32 bits

// ---------------- norms + arange ----------------
__global__ __launch_bounds__(256) void normk(const float* __restrict__ T, const float* __restrict__ E,
                                             float* __restrict__ invt, float* __restrict__ inve,
                                             float* __restrict__ out) {
  int row = blockIdx.x;
  const float* src = (row < 1024) ? (T + (size_t)row * 1024) : (E + (size_t)(row - 1024) * 1024);
  int tid = threadIdx.x;
  float4 v = ((const float4*)src)[tid];
  float s = v.x * v.x + v.y * v.y + v.z * v.z + v.w * v.w;
  #pragma unroll
  for (int d = 1; d < 64; d <<= 1) s += __shfl_xor(s, d);
  __shared__ float wsum[4];
  if ((tid & 63) == 0) wsum[tid >> 6] = s;
  __syncthreads();
  if (tid == 0) {
    float tot = wsum[0] + wsum[1] + wsum[2] + wsum[3];
    float inv = 1.0f / fmaxf(sqrtf(tot), 1e-12f);
    if (row < 1024) invt[row] = inv; else inve[row - 1024] = inv;
  }
  if (blockIdx.x < 4) {
    int i = blockIdx.x * 256 + tid;
    out[1024 + i] = (float)i;
  }
}

__device__ inline unsigned keyOf(float f) {
  unsigned u = __float_as_uint(f);
  return (u & 0x80000000u) ? ~u : (u | 0x80000000u);
}

// ---------------- f32 GEMM: sim = (T . E^T) * invt * inve  (+ fused radix pass-0 hist) ----------------
#define AP 132
__global__ __launch_bounds__(256) void gemmk(const float* __restrict__ T, const float* __restrict__ E,
                                             const float* __restrict__ invt, const float* __restrict__ inve,
                                             float* __restrict__ sim, unsigned* __restrict__ hist) {
  __shared__ float As[16 * AP];
  __shared__ float Bs[16 * AP];
  __shared__ unsigned lh[4096];
  int tid = threadIdx.x;
  for (int b = tid; b < 4096; b += 256) lh[b] = 0;
  int i0 = blockIdx.y * 128;
  int j0 = blockIdx.x * 128;
  int tx = tid & 15, ty = tid >> 4;
  float acc[8][8];
  #pragma unroll
  for (int a = 0; a < 8; a++)
    #pragma unroll
    for (int b = 0; b < 8; b++) acc[a][b] = 0.f;

  int q = tid * 2;
  int r = q >> 2;
  int s4 = (q & 3) * 4;
  const float* Ag = T + (size_t)(i0 + r) * 1024 + s4;
  const float* Bg = E + (size_t)(j0 + r) * 1024 + s4;

  float4 a0 = *(const float4*)(Ag);
  float4 a1 = *(const float4*)(Ag + 4);
  float4 b0 = *(const float4*)(Bg);
  float4 b1 = *(const float4*)(Bg + 4);

  for (int kb = 0; kb < 64; kb++) {
    __syncthreads();
    As[(s4 + 0) * AP + r] = a0.x; As[(s4 + 1) * AP + r] = a0.y;
    As[(s4 + 2) * AP + r] = a0.z; As[(s4 + 3) * AP + r] = a0.w;
    As[(s4 + 4) * AP + r] = a1.x; As[(s4 + 5) * AP + r] = a1.y;
    As[(s4 + 6) * AP + r] = a1.z; As[(s4 + 7) * AP + r] = a1.w;
    Bs[(s4 + 0) * AP + r] = b0.x; Bs[(s4 + 1) * AP + r] = b0.y;
    Bs[(s4 + 2) * AP + r] = b0.z; Bs[(s4 + 3) * AP + r] = b0.w;
    Bs[(s4 + 4) * AP + r] = b1.x; Bs[(s4 + 5) * AP + r] = b1.y;
    Bs[(s4 + 6) * AP + r] = b1.z; Bs[(s4 + 7) * AP + r] = b1.w;
    __syncthreads();
    if (kb < 63) {
      a0 = *(const float4*)(Ag + (kb + 1) * 16);
      a1 = *(const float4*)(Ag + (kb + 1) * 16 + 4);
      b0 = *(const float4*)(Bg + (kb + 1) * 16);
      b1 = *(const float4*)(Bg + (kb + 1) * 16 + 4);
    }
    #pragma unroll
    for (int k = 0; k < 16; k++) {
      float a[8], b[8];
      *(float4*)&a[0] = *(float4*)&As[k * AP + ty * 8];
      *(float4*)&a[4] = *(float4*)&As[k * AP + ty * 8 + 4];
      *(float4*)&b[0] = *(float4*)&Bs[k * AP + tx * 8];
      *(float4*)&b[4] = *(float4*)&Bs[k * AP + tx * 8 + 4];
      #pragma unroll
      for (int ii = 0; ii < 8; ii++)
        #pragma unroll
        for (int jj = 0; jj < 8; jj++) acc[ii][jj] += a[ii] * b[jj];
    }
  }
  float ie[8];
  #pragma unroll
  for (int jj = 0; jj < 8; jj++) ie[jj] = inve[j0 + tx * 8 + jj];
  #pragma unroll
  for (int ii = 0; ii < 8; ii++) {
    float itv = invt[i0 + ty * 8 + ii];
    float o[8];
    #pragma unroll
    for (int jj = 0; jj < 8; jj++) o[jj] = acc[ii][jj] * itv * ie[jj];
    #pragma unroll
    for (int jj = 0; jj < 8; jj++) atomicAdd(&lh[keyOf(o[jj]) >> 20], 1u);
    float* dst = &sim[(size_t)(i0 + ty * 8 + ii) * 8192 + j0 + tx * 8];
    *(float4*)dst = *(float4*)&o[0];
    *(float4*)(dst + 4) = *(float4*)&o[4];
  }
  __syncthreads();
  for (int b = tid; b < 4096; b += 256) if (lh[b]) atomicAdd(&hist[b], lh[b]);
}

// ---------------- exact k-th largest: radix refine passes 1,2 (full-scan) ----------------
__global__ __launch_bounds__(256) void histk(const float* __restrict__ sim, unsigned* __restrict__ hist,
                                             const unsigned* __restrict__ sel, int pass) {
  __shared__ unsigned lh[4096];
  int tid = threadIdx.x;
  int nb = (pass == 2) ? 256 : 4096;
  for (int b = tid; b < nb; b += 256) lh[b] = 0;
  __syncthreads();
  unsigned prefix = sel[1];
  size_t base = (size_t)blockIdx.x * 4096 + tid * 4;
  #pragma unroll
  for (int it = 0; it < 4; it++) {
    float4 f = *(const float4*)(sim + base + it * 1024);
    float vals[4] = {f.x, f.y, f.z, f.w};
    #pragma unroll
    for (int e = 0; e < 4; e++) {
      unsigned u = keyOf(vals[e]);
      if (pass == 1) {
        if ((u >> 20) == (prefix >> 20)) atomicAdd(&lh[(u >> 8) & 0xFFFu], 1u);
      } else {
        if ((u >> 8) == (prefix >> 8)) atomicAdd(&lh[u & 0xFFu], 1u);
      }
    }
  }
  __syncthreads();
  for (int b = tid; b < nb; b += 256) if (lh[b]) atomicAdd(&hist[b], lh[b]);
}

__global__ __launch_bounds__(256) void scank(const unsigned* __restrict__ hist, unsigned* __restrict__ sel, int pass) {
  int tid = threadIdx.x;
  int nb = (pass == 2) ? 256 : 4096;
  int per = nb / 256;
  unsigned R = (pass == 0) ? 5872027u : sel[0];
  unsigned prefix = (pass == 0) ? 0u : sel[1];
  unsigned cnt[16];
  unsigned s = 0;
  for (int i = 0; i < per; i++) { cnt[i] = hist[tid * per + i]; s += cnt[i]; }
  unsigned incl = s;
  #pragma unroll
  for (int d = 1; d < 64; d <<= 1) { unsigned o = __shfl_up(incl, d); if ((tid & 63) >= d) incl += o; }
  __shared__ unsigned wt[4], wsc[4];
  if ((tid & 63) == 63) wt[tid >> 6] = incl;
  __syncthreads();
  if (tid < 4) {
    unsigned v = wt[tid];
    #pragma unroll
    for (int d = 1; d < 4; d <<= 1) { unsigned o = __shfl_up(v, d); if (tid >= d) v += o; }
    wsc[tid] = v;
  }
  __syncthreads();
  unsigned excl = incl - s + ((tid >> 6) ? wsc[(tid >> 6) - 1] : 0u);
  unsigned c = excl;
  for (int i = 0; i < per; i++) {
    unsigned nc = c + cnt[i];
    if (c < R && R <= nc) {
      unsigned bin = (unsigned)(tid * per + i);
      sel[0] = R - c;
      unsigned np_;
      if (pass == 0) np_ = bin << 20;
      else if (pass == 1) np_ = prefix | (bin << 8);
      else np_ = prefix | bin;
      sel[1] = np_;
      if (pass == 2) {
        unsigned key = np_;
        unsigned u = (key & 0x80000000u) ? (key ^ 0x80000000u) : ~key;
        ((float*)sel)[2] = __uint_as_float(u);
      }
    }
    c = nc;
  }
}

// ---------------- DPP helpers ----------------
template<int CTRL, int RM>
__device__ __forceinline__ float dppf(float old, float src) {
  return __int_as_float(__builtin_amdgcn_update_dpp(__float_as_int(old), __float_as_int(src), CTRL, RM, 0xf, false));
}
template<int CTRL, int RM>
__device__ __forceinline__ int dppi(int old, int src) {
  return __builtin_amdgcn_update_dpp(old, src, CTRL, RM, 0xf, false);
}

// full-wave shift-down-by-1 of x (lane l gets lane l-1's x; lane 0 gets `fill`)
__device__ __forceinline__ float wave_shr1(float x, float fill, int lane) {
  float rs  = dppf<0x111, 0xf>(INFV, x);
  float r15 = dppf<0x142, 0xa>(INFV, x);
  float r31 = dppf<0x143, 0xc>(INFV, x);
  float r = rs;
  if (lane == 16 || lane == 48) r = r15;
  if (lane == 32) r = r31;
  if (lane == 0) r = fill;
  return r;
}

// ---------------- Drop-DTW DP: 8-WG x 4-wave pipeline, depth-4 pinned ghop prefetch ----------------
// R21 structure + final mechanism completion: the depth-2 ghop prefetch sampled slot z at
// row z-2 while the lag-4 producer published z at the same moment (sample-at-publish race),
// and vmcnt(5) also stalled on STORE retirement (3 vmem ops/row -> steady outstanding ~6-9).
// Now: depth-4 prefetch (sample at z-4, fresh by >=2 rows vs the lag-6 stagger) consumed
// after vmcnt(11) (= 2+3+3+3 ops issued after the load by construction -> tolerates ~4 rows
// of in-flight loads/stores). Prologue rows 0..3 may read an incomplete register -> tag 0
// -> unchanged atomic spin (bit-exact always).
__global__ __launch_bounds__(256) void dpk(const float* __restrict__ sim,
                                           const unsigned* __restrict__ sel,
                                           unsigned long long* __restrict__ carryG,
                                           unsigned short* __restrict__ A, float* __restrict__ out) {
  int tid = threadIdx.x;
  int lane = tid & 63, w = tid >> 6;
  int wg = blockIdx.x;
  int W = wg * 4 + w;
  int col0 = wg * 1024 + tid * 4;
  float drop = ((const float*)sel)[2];
  __shared__ unsigned long long carry[3][1024];
  for (int i = tid; i < 3 * 1024; i += 256) ((unsigned long long*)carry)[i] = 0ull;
  __syncthreads();

  // startup stagger: ~512cy/unit; 1 row per lhop link, 6 rows per ghop link
  {
    int delayR = W + 5 * wg;
    for (int i = 0; i < delayR; ++i) __builtin_amdgcn_s_sleep(8);
  }

  bool ghop = (w == 0 && wg > 0);
  bool lhop = (w > 0);

  float r[4];
  #pragma unroll
  for (int u = 0; u < 4; u++) r[u] = 0.f;
  float rlast = 0.f;
  float pbfill = 0.f;
  int jj[4];
  #pragma unroll
  for (int u = 0; u < 4; u++) jj[u] = col0 + 1 + u;

  const float* zrow = sim + col0;
  unsigned short* abase = A + (size_t)(col0 >> 7) * 2048 + (col0 & 127);

  float b0[4], b1[4], b2[4], b3[4];
  *(float4*)&b0[0] = *(const float4*)(zrow);
  *(float4*)&b1[0] = *(const float4*)(zrow + 8192);
  *(float4*)&b2[0] = *(const float4*)(zrow + 16384);
  *(float4*)&b3[0] = *(const float4*)(zrow + 24576);

  const unsigned long long* gsrc = carryG + (size_t)(wg - 1) * 1024;
  unsigned long long pend = 0ull;
  unsigned long long pq0 = 0ull, pq1 = 0ull, pq2 = 0ull, pq3 = 0ull;  // depth-4 prefetch regs
  if (lhop) pend = __hip_atomic_load(&carry[w - 1][0], __ATOMIC_RELAXED, __HIP_MEMORY_SCOPE_WORKGROUP);
  if (ghop) {
    const unsigned long long* g0 = gsrc + 0;
    const unsigned long long* g1 = gsrc + 1;
    const unsigned long long* g2 = gsrc + 2;
    const unsigned long long* g3 = gsrc + 3;
    asm volatile("global_load_dwordx2 %0, %4, off sc0 sc1\n\t"
                 "global_load_dwordx2 %1, %5, off sc0 sc1\n\t"
                 "global_load_dwordx2 %2, %6, off sc0 sc1\n\t"
                 "global_load_dwordx2 %3, %7, off sc0 sc1"
                 : "+v"(pq0), "+v"(pq1), "+v"(pq2), "+v"(pq3)
                 : "v"(g0), "v"(g1), "v"(g2), "v"(g3) : "memory");
  }

  auto body = [&](float (&dc)[4], unsigned long long& pq, int zi0) {
    unsigned want = (unsigned)(zi0 + 1) << 14;

    // 1. consume carry FIRST. ghop: counted wait covers the depth-4 prefetch exactly
    //    (11 vmem ops issued after it); stale/incomplete -> tag miss -> atomic spin.
    if (ghop) {
      asm volatile("s_waitcnt vmcnt(11)" ::: "memory");
      __builtin_amdgcn_sched_barrier(0);
    }
    float cv; int ci;
    if (W > 0) {
      unsigned long long d = lhop ? pend : pq;
      if (__builtin_expect((((unsigned)d) & 0xFFFFC000u) != want, 0)) {
        int guard = 0;
        if (lhop) {
          do {
            __builtin_amdgcn_s_sleep(1);
            d = __hip_atomic_load(&carry[w - 1][zi0], __ATOMIC_RELAXED, __HIP_MEMORY_SCOPE_WORKGROUP);
          } while ((((unsigned)d) & 0xFFFFC000u) != want && ++guard < (1 << 20));
        } else {
          do {
            __builtin_amdgcn_s_sleep(1);
            d = __hip_atomic_load(gsrc + zi0, __ATOMIC_RELAXED, __HIP_MEMORY_SCOPE_AGENT);
          } while ((((unsigned)d) & 0xFFFFC000u) != want && ++guard < (1 << 20));
        }
      }
      cv = __uint_as_float((unsigned)(d >> 32));
      ci = (int)((unsigned)d & 0x3FFFu);
    } else {
      cv = INFV; ci = 0;
    }
    // 2. re-arm carry prefetch: LDS depth-1 (completion pinned at end of body),
    //    global depth-4 (asm, issue pinned; slot zi0+4 clamped)
    if (lhop && zi0 + 1 < 1024) pend = __hip_atomic_load(&carry[w - 1][zi0 + 1], __ATOMIC_RELAXED, __HIP_MEMORY_SCOPE_WORKGROUP);
    if (ghop) {
      int slot = zi0 + 4; if (slot > 1023) slot = 1023;
      const unsigned long long* gp = gsrc + slot;
      asm volatile("global_load_dwordx2 %0, %1, off sc0 sc1" : "+v"(pq) : "v"(gp) : "memory");
    }

    // 3. row compute: tv = (drop - sim) + B_prev  (identical ops/order to reference)
    float fill = (W == 0) ? ((zi0 == 0) ? 0.f : INFV) : pbfill;
    float pb0 = wave_shr1(rlast, fill, lane);
    float tv[4];
    { float zx0 = drop - dc[0]; tv[0] = zx0 + pb0; }
    #pragma unroll
    for (int u = 1; u < 4; u++) { float zxu = drop - dc[u]; tv[u] = zxu + r[u - 1]; }
    // 4. sim prefetch re-arm (unconditional, clamped row -> 3 vmem ops per row invariant)
    {
      int nr = zi0 + 4; if (nr > 1023) nr = 1023;
      *(float4*)&dc[0] = *(const float4*)(zrow + (size_t)nr * 8192);
    }
    // 5. in-thread inclusive prefix-min + latest-tie argmin
    int li[4];
    r[0] = tv[0]; li[0] = jj[0];
    #pragma unroll
    for (int u = 1; u < 4; u++) {
      bool t = (tv[u] <= r[u - 1]);
      r[u] = t ? tv[u] : r[u - 1];
      li[u] = t ? jj[u] : li[u - 1];
    }
    float v = r[3]; int ix = li[3];
    { float sv = dppf<0x111, 0xf>(INFV, v); int si = dppi<0x111, 0xf>(0, ix); if (sv < v) { v = sv; ix = si; } }
    { float sv = dppf<0x112, 0xf>(INFV, v); int si = dppi<0x112, 0xf>(0, ix); if (sv < v) { v = sv; ix = si; } }
    { float sv = dppf<0x114, 0xf>(INFV, v); int si = dppi<0x114, 0xf>(0, ix); if (sv < v) { v = sv; ix = si; } }
    { float sv = dppf<0x118, 0xf>(INFV, v); int si = dppi<0x118, 0xf>(0, ix); if (sv < v) { v = sv; ix = si; } }
    { float sv = dppf<0x142, 0xa>(INFV, v); int si = dppi<0x142, 0xa>(0, ix); if (sv < v) { v = sv; ix = si; } }
    { float sv = dppf<0x143, 0xc>(INFV, v); int si = dppi<0x143, 0xc>(0, ix); if (sv < v) { v = sv; ix = si; } }
    float exv = dppf<0x111, 0xf>(INFV, v); int exi = dppi<0x111, 0xf>(0, ix);
    float e15 = dppf<0x142, 0xa>(INFV, v); int i15 = dppi<0x142, 0xa>(0, ix);
    float e31 = dppf<0x143, 0xc>(INFV, v); int i31 = dppi<0x143, 0xc>(0, ix);
    if (lane == 16 || lane == 48) { exv = e15; exi = i15; }
    if (lane == 32) { exv = e31; exi = i31; }

    // 6. publish combined C_W(zi0) = combine(C_{W-1}, T_W); own cols later -> win ties
    if (lane == 63 && W < 31) {
      bool t = (v <= cv);
      float cov = t ? v : cv;
      int coi = t ? ix : ci;
      unsigned long long pd = ((unsigned long long)__float_as_uint(cov) << 32)
                            | (unsigned)(coi & 0x3FFF) | (unsigned long long)want;
      if (w < 3) __hip_atomic_store(&carry[w][zi0], pd, __ATOMIC_RELAXED, __HIP_MEMORY_SCOPE_WORKGROUP);
      else       __hip_atomic_store(&carryG[(size_t)wg * 1024 + zi0], pd, __ATOMIC_RELAXED, __HIP_MEMORY_SCOPE_AGENT);
    }

    // 7. init = combine(received carry, wave-exclusive); PARALLEL per-column merge; A-store
    float pv; int pi;
    { bool t = (exv <= cv); pv = t ? exv : cv; pi = t ? exi : ci; }
    #pragma unroll
    for (int u = 0; u < 4; u++) {
      bool t = (r[u] <= pv);
      r[u] = t ? r[u] : pv;
      li[u] = t ? li[u] : pi;
    }
    rlast = r[3];
    pbfill = cv;

    unsigned pk0 = (unsigned)li[0] | ((unsigned)li[1] << 16);
    unsigned pk1 = (unsigned)li[2] | ((unsigned)li[3] << 16);
    *(uint2*)(abase + (size_t)(zi0 >> 4) * (64 * 2048) + ((zi0 & 15) << 7)) = make_uint2(pk0, pk1);

    // 8. pin lhop prefetch completion at end of body
    if (lhop) asm volatile("" : "+v"(pend));
  };

  for (int zz = 0; zz < 1024; zz += 4) {
    body(b0, pq0, zz);
    body(b1, pq1, zz + 1);
    body(b2, pq2, zz + 2);
    body(b3, pq3, zz + 3);
  }
  if (wg == 7 && tid == 255) out[2048] = rlast;   // min(D0f[K,N], D1f[K,N])
}

// ---------------- parallel backtrack ----------------
__global__ __launch_bounds__(256) void btk1(const unsigned short* __restrict__ A,
                                            unsigned short* __restrict__ map) {
  int g = blockIdx.x * 256 + threadIdx.x;
  int b = g >> 13;
  int j = (g & 8191) + 1;
  #pragma unroll
  for (int s = 15; s >= 0; --s) {
    int col = (j > 0) ? (j - 1) : 0;
    int p = A[(size_t)(b * 64 + (col >> 7)) * 2048 + (s << 7) + (col & 127)];
    j = p - 1;
  }
  map[g] = (unsigned short)j;
}

__global__ void btk2(const unsigned short* __restrict__ A, const unsigned short* __restrict__ map,
                     float* __restrict__ out) {
  __shared__ int entry[64];
  int t = threadIdx.x;
  if (t == 0) {
    int jb = 8192;
    for (int b = 63; b >= 0; --b) {
      entry[b] = jb;
      jb = map[b * 8192 + (jb - 1)];
    }
  }
  __syncthreads();
  if (t < 64) {
    int b = t;
    int j = entry[b];
    for (int s = 15; s >= 0; --s) {
      int col = j - 1;
      int p = A[(size_t)(b * 64 + (col >> 7)) * 2048 + (s << 7) + (col & 127)];
      out[b * 16 + s] = (float)(p - 1);
      j = p - 1;
    }
  }
}

extern "C" void kernel_launch(void* const* d_in, const int* in_sizes, int n_in,
                              void* d_out, int out_size, void* d_ws, size_t ws_size,
                              hipStream_t stream) {
  (void)in_sizes; (void)n_in; (void)out_size; (void)ws_size;
  const float* T = (const float*)d_in[0];
  const float* E = (const float*)d_in[1];
  char* ws = (char*)d_ws;
  float* sim = (float*)(ws + SIM_OFF);
  unsigned short* A = (unsigned short*)(ws + A_OFF);
  float* invt = (float*)(ws + INVT_OFF);
  float* inve = (float*)(ws + INVE_OFF);
  unsigned* h1 = (unsigned*)(ws + H1_OFF);
  unsigned* h2 = (unsigned*)(ws + H2_OFF);
  unsigned* h3 = (unsigned*)(ws + H3_OFF);
  unsigned* sel = (unsigned*)(ws + SEL_OFF);
  unsigned long long* carryG = (unsigned long long*)(ws + INVT_OFF);
  unsigned short* map = (unsigned short*)(ws + SIM_OFF);
  float* out = (float*)d_out;

  hipMemsetAsync(ws + H1_OFF, 0, 16384 + 16384 + 1024 + 64, stream);
  normk<<<9216, 256, 0, stream>>>(T, E, invt, inve, out);
  gemmk<<<dim3(64, 8), 256, 0, stream>>>(T, E, invt, inve, sim, h1);   // fused pass-0 hist
  scank<<<1, 256, 0, stream>>>(h1, sel, 0);
  histk<<<2048, 256, 0, stream>>>(sim, h2, sel, 1);
  scank<<<1, 256, 0, stream>>>(h2, sel, 1);
  histk<<<2048, 256, 0, stream>>>(sim, h3, sel, 2);
  scank<<<1, 256, 0, stream>>>(h3, sel, 2);
  hipMemsetAsync(ws + INVT_OFF, 0, 7 * 1024 * 8, stream);   // zero carryG
  dpk<<<8, 256, 0, stream>>>(sim, sel, carryG, A, out);
  btk1<<<2048, 256, 0, stream>>>(A, map);
  btk2<<<1, 64, 0, stream>>>(A, map, out);
}